// Round 8
// baseline (183.117 us; speedup 1.0000x reference)
//
#include <hip/hip_runtime.h>
#include <hip/hip_cooperative_groups.h>

namespace cg = cooperative_groups;

// GaussianHistogram: hist[b,i,j] = sum_n exp(-pi*(u1-i)^2) * exp(-pi*(u2-j)^2) * mask
// u = (x - MIN_V)/DELTA - 0.5 ; COEF == 1.0 exactly.
//
// v8b: v8 with the kC1 literal typo fixed (compile error last round; design
// untested until now). ONE COOPERATIVE DISPATCH: scatter-partials -> grid.sync
// -> reduce. Model from v1-v7: dur ~= 41us harness ws-fill (fixed, HBM-bound)
//   + ~12us per EXTRA kernel boundary (v7's 3 dispatches -> 95us regression)
//   + per-CU point-evals * ~1.1ns (v5->v6: evals/CU 32768->16384, 37->~19us)
// So: kill all inter-dispatch gaps (cooperative grid.sync) AND cut evals/CU to
// 8192 (TROWS=32 row-tiles x CHUNK=4 point chunks: 256 blocks, 1/CU).
//
// Deposit math = v5/v6 (passed, absmax 0.0156): 3 exact row taps x one 4-col
// 16-bit-field u64 word; two phase-shifted packings (phase0 words cols 4w..,
// phase1 cols 4w+2..) so the col window [j0-1,j0+1] fits one word; 4th field =
// exact bonus tap. ds_add_u64 into 32KB LDS partial tile; partials -> ws;
// grid.sync (+threadfence: agent release/acquire = L2 wb, cross-XCD safe);
// reduce unpacks+sums 4 chunks -> out. Dropped taps >=1.5 bins (w<=8.5e-4);
// .10 fixed point, per-chunk field load 4x below v5's (no carry).
//
// Exp factorization (4 exp + 2 rcp per eval, was 7 exp):
//   rows:  w(-1),w(0),w(+1) = w0*K*E, w0, w0*K/E; w0=e^{-pi t1^2}, E=e^{-2pi t1},
//          K=e^{-pi}.
//   cols (s = t2-1.5, dist d = s+1.5-c): W_c = P * Q^{3,1,-1,-3} * {C2,C1,C1,C2};
//          P=e^{-pi s^2}, Q=e^{-pi s}, C1=e^{-pi/4}, C2=e^{-9pi/4}.

#define BINS   256
#define NPTS   32768
#define BATCH  8
#define TROWS  32                  // rows per tile
#define NTILE  (BINS / TROWS)      // 8
#define CHUNK  4                   // point chunks per batch
#define PPC    (NPTS / CHUNK)      // 8192
#define WORDS  64                  // u64 words per row per phase
#define TILE64 (2 * TROWS * WORDS) // 4096 u64 = 32 KB
#define NBLK   (BATCH * NTILE * CHUNK) // 256 blocks, 1/CU

static constexpr float kInvDelta = 256.0f / 1.5f;                  // 1/DELTA
static constexpr float kUAdd     = 0.25f * (256.0f / 1.5f) - 0.5f; // (x-MIN)/D - 0.5
static constexpr float kPi       = 3.14159265358979323846f;
static constexpr float kTwoPi    = 6.28318530717958647692f;
static constexpr float kEmPi     = 0.043213918263772250f;   // exp(-pi)
static constexpr float kC1       = 0.4559381277659962f;     // exp(-0.25*pi)
static constexpr float kC2       = 8.514366756432101e-4f;   // exp(-2.25*pi)
static constexpr float kFix      = 1024.0f;                 // .10 fixed point
static constexpr float kInvFix   = 1.0f / 1024.0f;

__global__ __launch_bounds__(512, 2) void gh_all(
    const float* __restrict__ x1, const float* __restrict__ x2,
    const float* __restrict__ mask, unsigned long long* __restrict__ ws,
    float* __restrict__ out)
{
    __shared__ unsigned long long tile[TILE64];   // 32 KB
    const int tid = threadIdx.x;
    const int blk = blockIdx.x;
    const int b   = blk >> 5;          // NTILE*CHUNK = 32
    const int t   = (blk >> 2) & 7;
    const int z   = blk & 3;
    const int r0  = t * TROWS;

    // ---------------- phase A: scatter chunk z into LDS partial tile --------
#pragma unroll
    for (int i = tid; i < TILE64; i += 512) tile[i] = 0ULL;
    __syncthreads();

    const float4* X1 = (const float4*)(x1   + b * NPTS + z * PPC);
    const float4* X2 = (const float4*)(x2   + b * NPTS + z * PPC);
    const float4* M  = (const float4*)(mask + b * NPTS + z * PPC);

#pragma unroll
    for (int it = 0; it < PPC / 2048; ++it) {     // 4 iterations, 4 points each
        const int n4 = it * 512 + tid;
        const float4 a4 = X1[n4];
        const float4 b4 = X2[n4];
        const float4 m4 = M[n4];

        const float pv1[4] = {a4.x, a4.y, a4.z, a4.w};
        const float pv2[4] = {b4.x, b4.y, b4.z, b4.w};
        const float pm[4]  = {m4.x, m4.y, m4.z, m4.w};

#pragma unroll
        for (int k = 0; k < 4; ++k) {
            const float u1 = fmaf(pv1[k], kInvDelta, kUAdd);
            const float u2 = fmaf(pv2[k], kInvDelta, kUAdd);
            const float fi = rintf(u1);
            int i0 = (int)fi;
            i0 = min(254, max(1, i0));
            const float t1 = u1 - fi;              // [-0.5, 0.5]

            int e = (((int)rintf(u2)) - 1) & ~1;
            e = min(250, max(0, e));
            const int  ph   = (e >> 1) & 1;
            const int  word = e >> 2;
            const float s   = (u2 - (float)e) - 1.5f;  // [-1, 1]

            // row weights via factorization
            const float w0  = __expf(-kPi * t1 * t1);
            const float E   = __expf(-kTwoPi * t1);
            const float iE  = __builtin_amdgcn_rcpf(E);
            const float w0K = w0 * kEmPi;
            const float wr0 = w0K * E;
            const float wr2 = w0K * iE;

            // col weights via factorization (mask + fixed scale folded in)
            const float P   = __expf(-kPi * s * s);
            const float Q   = __expf(-kPi * s);
            const float iQ  = __builtin_amdgcn_rcpf(Q);
            const float Q3  = Q * Q * Q;
            const float iQ3 = iQ * iQ * iQ;
            const float pmF = pm[k] * kFix;
            const float PC1 = P * (kC1 * pmF);
            const float PC2 = P * (kC2 * pmF);
            const float W0 = PC2 * Q3, W1 = PC1 * Q, W2v = PC1 * iQ, W3 = PC2 * iQ3;

            const int rbase = i0 - 1 - r0;
            const int pbase = ph * (TROWS * WORDS) + word;
            const float wra[3] = {wr0, w0, wr2};
#pragma unroll
            for (int a = 0; a < 3; ++a) {
                const int r = rbase + a;
                if ((unsigned)r < TROWS) {
                    const float wa = wra[a];
                    const unsigned f0 = (unsigned)fmaf(wa, W0, 0.5f);
                    const unsigned f1 = (unsigned)fmaf(wa, W1, 0.5f);
                    const unsigned f2 = (unsigned)fmaf(wa, W2v, 0.5f);
                    const unsigned f3 = (unsigned)fmaf(wa, W3, 0.5f);
                    const unsigned long long w =
                        (unsigned long long)(f0 | (f1 << 16)) |
                        ((unsigned long long)(f2 | (f3 << 16)) << 32);
                    atomicAdd(&tile[pbase + r * WORDS], w);   // ds_add_u64
                }
            }
        }
    }
    __syncthreads();

    // store partial tile (fully, zeros included) to ws[blk]
    {
        unsigned long long* W = ws + (size_t)blk * TILE64;
#pragma unroll
        for (int i = tid; i < TILE64; i += 512) W[i] = tile[i];
    }
    __threadfence();                 // agent-scope release (L2 writeback)
    cg::this_grid().sync();          // all partials visible device-wide
    __threadfence();                 // acquire side

    // ---------------- phase B: reduce 4 chunks, unpack phases, store out ----
    // this block reduces rows [z*8 .. z*8+8) interleaved of tile t, batch b.
    const int r_l = tid >> 7;            // 0..3
    const int c0  = (tid & 127) * 2;     // even col
#pragma unroll
    for (int ii = 0; ii < 2; ++ii) {
        const int rt = z * 8 + r_l + ii * 4;    // row within 32-row tile
        unsigned a0 = 0, a1 = 0;
#pragma unroll
        for (int zz = 0; zz < CHUNK; ++zz) {
            const unsigned long long* Zp =
                ws + (size_t)(((b * NTILE + t) * CHUNK + zz)) * TILE64;
            const unsigned long long we = Zp[rt * WORDS + (c0 >> 2)];
            const int sh = 16 * (c0 & 3);
            a0 += (unsigned)(we >> sh)        & 0xFFFFu;
            a1 += (unsigned)(we >> (sh + 16)) & 0xFFFFu;     // same word, c0 even
            if (c0 >= 2) {
                const unsigned long long wo =
                    Zp[TROWS * WORDS + rt * WORDS + ((c0 - 2) >> 2)];
                const int sho = 16 * ((c0 - 2) & 3);
                a0 += (unsigned)(wo >> sho)        & 0xFFFFu;
                a1 += (unsigned)(wo >> (sho + 16)) & 0xFFFFu; // same word
            }
        }
        float2 f;
        f.x = (float)a0 * kInvFix;
        f.y = (float)a1 * kInvFix;
        *(float2*)(out + ((size_t)b * BINS + r0 + rt) * BINS + c0) = f;
    }
}

extern "C" void kernel_launch(void* const* d_in, const int* in_sizes, int n_in,
                              void* d_out, int out_size, void* d_ws, size_t ws_size,
                              hipStream_t stream) {
    const float* x1   = (const float*)d_in[0];
    const float* x2   = (const float*)d_in[1];
    const float* mask = (const float*)d_in[2];
    float*       out  = (float*)d_out;
    unsigned long long* ws = (unsigned long long*)d_ws;

    void* args[] = {(void*)&x1, (void*)&x2, (void*)&mask, (void*)&ws, (void*)&out};
    (void)hipLaunchCooperativeKernel((const void*)gh_all, dim3(NBLK), dim3(512),
                                     args, 0, stream);
}